// Round 6
// baseline (2183.766 us; speedup 1.0000x reference)
//
#include <hip/hip_runtime.h>

typedef float f32x4 __attribute__((ext_vector_type(4)));
typedef float f32x16 __attribute__((ext_vector_type(16)));
typedef short bf16x8 __attribute__((ext_vector_type(8)));

#define DEVI __device__ __forceinline__

// ---------- constants (problem shape is fixed) ----------
constexpr int Bn = 2;          // batch
constexpr int Sn = 4096;       // seq
constexpr int Hn = 16;         // heads
constexpr int Dn = 128;        // head dim
constexpr int En = 2048;       // d_model = Hn*Dn
constexpr int Mtot = Bn * Sn;  // 8192 token rows

DEVI unsigned short f2bf(float f) {
  unsigned u = __float_as_uint(f);
  u += 0x7fffu + ((u >> 16) & 1u);
  return (unsigned short)(u >> 16);
}
DEVI float bf2f(unsigned short h) {
  return __uint_as_float(((unsigned)h) << 16);
}
DEVI unsigned pk2(float a, float b) {
  return (unsigned)f2bf(a) | ((unsigned)f2bf(b) << 16);
}

DEVI void async16(const void* g, void* l) {
  __builtin_amdgcn_global_load_lds(
      (const __attribute__((address_space(1))) void*)g,
      (__attribute__((address_space(3))) void*)l, 16, 0, 0);
}

// Pack 8 fp32 P-values (S^T regs of one j-subtile) into the PV B-operand
// fragment for one mfma_32x32x16 k-slot (elem e -> j = hi*8 + e; lane keeps
// q-col = lane&31). shfl_xor(32) + select; proven correct in round 5.
DEVI bf16x8 pack_pa(float a0, float a1, float a2, float a3,
                    float a4, float a5, float a6, float a7, int hi) {
  unsigned w0 = pk2(a0, a1), w1 = pk2(a2, a3);
  unsigned y0 = pk2(a4, a5), y1 = pk2(a6, a7);
  unsigned x0 = __shfl_xor(w0, 32), x1 = __shfl_xor(w1, 32);
  unsigned z0 = __shfl_xor(y0, 32), z1 = __shfl_xor(y1, 32);
  union { unsigned u[4]; bf16x8 v; } r;
  r.u[0] = hi ? z0 : w0;
  r.u[1] = hi ? z1 : w1;
  r.u[2] = hi ? y0 : x0;
  r.u[3] = hi ? y1 : x1;
  return r.v;
}

// ---------- fp32 -> bf16 convert ----------
__global__ void cvt_kernel(const float* __restrict__ in, ushort* __restrict__ out) {
  size_t i = ((size_t)blockIdx.x * 256 + threadIdx.x) * 4;
  float4 v = *(const float4*)&in[i];
  ushort4 o;
  o.x = f2bf(v.x); o.y = f2bf(v.y); o.z = f2bf(v.z); o.w = f2bf(v.w);
  *(ushort4*)&out[i] = o;
}

// ---------- GEMM: C[M,N] = A[M,K] * B[N,K]^T, bf16 in, fp32 acc ----------
// EPI 0: bf16 C row-major [Mtot, En]
// EPI 1: bf16 transposed V: Vt[(b*En + n)*Sn + s]  (m = b*Sn + s)
// EPI 2: fp32 C row-major
// EPI 3: bf16 C row-major with fused RoPE (interleaved pairs) * scale
template <int EPI>
__global__ __launch_bounds__(256) void gemm_bt(const ushort* __restrict__ A,
                                               const ushort* __restrict__ Bm,
                                               void* __restrict__ Cv,
                                               float scale) {
  __shared__ ushort As[128 * 64];
  __shared__ ushort Bs[128 * 64];
  const int t = threadIdx.x;
  const int lane = t & 63, w = t >> 6;
  const int ln = lane & 15, gq = lane >> 4;
  const int m0 = blockIdx.y * 128, n0 = blockIdx.x * 128;
  const int rm = (w >> 1) * 64, rn = (w & 1) * 64;
  f32x4 acc[4][4] = {};

  for (int k0 = 0; k0 < En; k0 += 64) {
#pragma unroll
    for (int rep = 0; rep < 4; ++rep) {
      int c = rep * 256 + t;       // chunk 0..1023 (16B each)
      int row = c >> 3, c8 = c & 7;
      async16(&A[(size_t)(m0 + row) * En + k0 + c8 * 8],
              (char*)As + (rep * 256 + w * 64) * 16);
      async16(&Bm[(size_t)(n0 + row) * En + k0 + c8 * 8],
              (char*)Bs + (rep * 256 + w * 64) * 16);
    }
    __syncthreads();
#pragma unroll
    for (int kk = 0; kk < 64; kk += 32) {
      bf16x8 af[4], bf[4];
#pragma unroll
      for (int i = 0; i < 4; ++i)
        af[i] = *(const bf16x8*)&As[(rm + i * 16 + ln) * 64 + kk + gq * 8];
#pragma unroll
      for (int j = 0; j < 4; ++j)
        bf[j] = *(const bf16x8*)&Bs[(rn + j * 16 + ln) * 64 + kk + gq * 8];
#pragma unroll
      for (int i = 0; i < 4; ++i)
#pragma unroll
        for (int j = 0; j < 4; ++j)
          acc[i][j] = __builtin_amdgcn_mfma_f32_16x16x32_bf16(af[i], bf[j], acc[i][j], 0, 0, 0);
    }
    __syncthreads();
  }

  if constexpr (EPI == 0) {
    ushort* C = (ushort*)Cv;
#pragma unroll
    for (int i = 0; i < 4; ++i) {
      int row0 = m0 + rm + i * 16 + gq * 4;
#pragma unroll
      for (int j = 0; j < 4; ++j) {
        int col = n0 + rn + j * 16 + ln;
#pragma unroll
        for (int r = 0; r < 4; ++r)
          C[(size_t)(row0 + r) * En + col] = f2bf(acc[i][j][r]);
      }
    }
  } else if constexpr (EPI == 1) {
    ushort* Vt = (ushort*)Cv;
#pragma unroll
    for (int i = 0; i < 4; ++i) {
      int mrow = m0 + rm + i * 16 + gq * 4;   // token row (4 consecutive)
      int bb = mrow >> 12;                     // /Sn
      int ss = mrow & (Sn - 1);
#pragma unroll
      for (int j = 0; j < 4; ++j) {
        int col = n0 + rn + j * 16 + ln;       // e = h*128+d
        ushort4 pk;
        pk.x = f2bf(acc[i][j][0]); pk.y = f2bf(acc[i][j][1]);
        pk.z = f2bf(acc[i][j][2]); pk.w = f2bf(acc[i][j][3]);
        *(ushort4*)&Vt[((size_t)(bb * En + col)) * Sn + ss] = pk;
      }
    }
  } else if constexpr (EPI == 2) {
    float* C = (float*)Cv;
#pragma unroll
    for (int i = 0; i < 4; ++i) {
      int row0 = m0 + rm + i * 16 + gq * 4;
#pragma unroll
      for (int j = 0; j < 4; ++j) {
        int col = n0 + rn + j * 16 + ln;
#pragma unroll
        for (int r = 0; r < 4; ++r)
          C[(size_t)(row0 + r) * En + col] = acc[i][j][r];
      }
    }
  } else {
    // EPI 3: fused RoPE. Pair partner (col^1) lives on lane^1 (col tracks ln).
    ushort* C = (ushort*)Cv;
    const int odd = ln & 1;
#pragma unroll
    for (int i = 0; i < 4; ++i) {
      int row0 = m0 + rm + i * 16 + gq * 4;
#pragma unroll
      for (int j = 0; j < 4; ++j) {
        int col = n0 + rn + j * 16 + ln;
        int pp = (col & (Dn - 1)) >> 1;  // pair index within head, 0..63
        float inv = exp2f(-(float)pp * (13.287712379549449f / 64.0f));
#pragma unroll
        for (int r = 0; r < 4; ++r) {
          int row = row0 + r;
          float ang = (float)(row & (Sn - 1)) * inv;
          float cs = cosf(ang), sn = sinf(ang);
          float self = acc[i][j][r];
          float other = __shfl_xor(self, 1);
          float val = odd ? (self * cs + other * sn) : (self * cs - other * sn);
          C[(size_t)row * En + col] = f2bf(val * scale);
        }
      }
    }
  }
}

// ---------- flash attention (causal), 32x32 swapped-QK^T, in-register P ----
// Q: [Mtot,En] bf16 (RoPE + 1/sqrt(d)*log2e fused in GEMM). K: [Mtot,En].
// Vt: [B*En, Sn] bf16 (V transposed). Out Ab: [Mtot, En] bf16.
// Block: 4 waves x 32 q-rows = 128 q-rows. KV tile = 64.
// K/V double-buffered (T3/T4): issue tile t+1's 8 gload_lds per wave, then
// wait vmcnt(8) (tile t retired, t+1 in flight) -- never vmcnt(0) mid-loop.
// LDS 64KB -> 2 blocks/CU (reg limit anyway; pinned via launch_bounds(256,2)).
// S^T = mfma32(K, Q): lane owns q-col = lane&31 end-to-end.
// PV as O^T = mfma32(A=V^T, B=P): C[m=d][n=q] keeps q on lanes.
// Ks swizzle: 16B-slot ^= (j&15); Vs: slot ^= (d&7) (both-sides rule #21).
__global__ __launch_bounds__(256, 2) void flash_kernel(const ushort* __restrict__ Qb,
                                                       const ushort* __restrict__ Kb,
                                                       const ushort* __restrict__ Vt,
                                                       ushort* __restrict__ Ab) {
  __shared__ ushort Ks[2][64 * 128];   // [buf][kv j][d], swizzled
  __shared__ ushort Vs[2][128 * 64];   // [buf][d][kv j], swizzled
  const int t = threadIdx.x;
  const int lane = t & 63, w = t >> 6;
  const int l31 = lane & 31, hi = lane >> 5;

  // XCD-chunked decode: orig%8 = xcd, 4 bh per xcd, heavy qtile first (LPT)
  const int orig = blockIdx.x;         // 0..1023
  const int pos = orig >> 3;           // 0..127
  const int bh = ((orig & 7) << 2) + (pos >> 5);
  const int qt = 31 - (pos & 31);      // heavy-first
  const int q0 = qt * 128;
  const int b = bh >> 4, h = bh & 15;

  const int qrow = q0 + w * 32 + l31;  // this lane's q column

  // Q B-fragments: qf[ks] covers d = ks*16 + hi*8 + {0..7}
  bf16x8 qf[8];
  {
    size_t qbase = ((size_t)(b * Sn + qrow)) * En + h * Dn + hi * 8;
#pragma unroll
    for (int ks = 0; ks < 8; ++ks)
      qf[ks] = *(const bf16x8*)&Qb[qbase + ks * 16];
  }

  f32x16 o[4] = {};                    // O^T: [dsub] C[m=d][n=q], q on lanes
  float m_prev = -1e30f, l_prev = 0.f;
  const int last = 2 * qt + 1;         // tiles tt=0..last, j0 = tt*64

  // stage tile jt0 (elements) into buffer bufi: 8 gload_lds per wave
  auto stage = [&](int jt0, int bufi) {
#pragma unroll
    for (int rep = 0; rep < 4; ++rep) {
      int c = rep * 256 + t;
      int krow = c >> 4, ksl = c & 15;
      int kc = ksl ^ (krow & 15);          // inverse swizzle on global chunk
      async16(&Kb[((size_t)(b * Sn + jt0 + krow)) * En + h * Dn + kc * 8],
              (char*)&Ks[bufi][0] + (rep * 256 + w * 64) * 16);
      int vrow = c >> 3, vsl = c & 7;
      int vc = vsl ^ (vrow & 7);
      async16(&Vt[((size_t)(b * En + h * Dn + vrow)) * Sn + jt0 + vc * 8],
              (char*)&Vs[bufi][0] + (rep * 256 + w * 64) * 16);
    }
  };

  stage(0, 0);  // prologue: tile 0 in flight

  for (int tt = 0; tt <= last; ++tt) {
    const int cur = tt & 1;
    const int j0 = tt << 6;
    // B1: all waves finished reading buf[cur^1] -> safe to overwrite
    __builtin_amdgcn_s_barrier();
    if (tt < last) {
      stage((tt + 1) << 6, cur ^ 1);                    // 8 new in flight
      asm volatile("s_waitcnt vmcnt(8)" ::: "memory");  // tile tt retired
    } else {
      asm volatile("s_waitcnt vmcnt(0)" ::: "memory");
    }
    // B2: every wave's tile-tt DMA retired -> LDS tile complete
    __builtin_amdgcn_s_barrier();
    __builtin_amdgcn_sched_barrier(0);

    // waves whose q range is entirely above this kv tile skip compute
    if (j0 <= q0 + w * 32 + 31) {
      // ---- S^T: C[m=j][n=q] via mfma32(K, Q), 2 j-subtiles, 8 k-slots
      f32x16 s0 = {}, s1 = {};
      __builtin_amdgcn_s_setprio(1);
#pragma unroll
      for (int ks = 0; ks < 8; ++ks) {
        int soff = ((ks * 2 + hi) ^ (l31 & 15)) << 3;
        bf16x8 kf0 = *(const bf16x8*)&Ks[cur][l31 * 128 + soff];
        bf16x8 kf1 = *(const bf16x8*)&Ks[cur][(32 + l31) * 128 + soff];
        s0 = __builtin_amdgcn_mfma_f32_32x32x16_bf16(kf0, qf[ks], s0, 0, 0, 0);
        s1 = __builtin_amdgcn_mfma_f32_32x32x16_bf16(kf1, qf[ks], s1, 0, 0, 0);
      }
      __builtin_amdgcn_s_setprio(0);

      // ---- online softmax (lane owns one q-col; partner lane^32 has the
      // complementary 32 of the 64 kv rows)
      float mx = -1e30f;
      if (j0 + 63 > q0 + w * 32) {   // masking needed for this wave
#pragma unroll
        for (int r = 0; r < 16; ++r) {
          int jj = j0 + (r & 3) + 8 * (r >> 2) + 4 * hi;
          if (jj > qrow) s0[r] = -1e30f;
          if (jj + 32 > qrow) s1[r] = -1e30f;
          mx = fmaxf(mx, fmaxf(s0[r], s1[r]));
        }
      } else {
#pragma unroll
        for (int r = 0; r < 16; ++r)
          mx = fmaxf(mx, fmaxf(s0[r], s1[r]));
      }
      mx = fmaxf(mx, __shfl_xor(mx, 32));

      float mn;
      if (__all(mx - m_prev <= 8.f)) {   // defer-max (T13)
        mn = m_prev;
      } else {
        mn = fmaxf(m_prev, mx);
        float alpha = exp2f(m_prev - mn);
        m_prev = mn;
        l_prev *= alpha;
#pragma unroll
        for (int d = 0; d < 4; ++d) o[d] *= alpha;
      }
      float sum = 0.f;
#pragma unroll
      for (int r = 0; r < 16; ++r) {
        float p0 = exp2f(s0[r] - mn);
        float p1 = exp2f(s1[r] - mn);
        s0[r] = p0; s1[r] = p1;
        sum += p0 + p1;
      }
      sum += __shfl_xor(sum, 32);
      l_prev += sum;

      // ---- P -> PV B-fragments in registers (no LDS round-trip)
      bf16x8 pa[4];
      pa[0] = pack_pa(s0[0], s0[1], s0[2], s0[3], s0[4], s0[5], s0[6], s0[7], hi);
      pa[1] = pack_pa(s0[8], s0[9], s0[10], s0[11], s0[12], s0[13], s0[14], s0[15], hi);
      pa[2] = pack_pa(s1[0], s1[1], s1[2], s1[3], s1[4], s1[5], s1[6], s1[7], hi);
      pa[3] = pack_pa(s1[8], s1[9], s1[10], s1[11], s1[12], s1[13], s1[14], s1[15], hi);

      // ---- PV as O^T: C[m=d][n=q] = sum_j V^T[d][j] P[j][q]
      __builtin_amdgcn_s_setprio(1);
#pragma unroll
      for (int dsub = 0; dsub < 4; ++dsub) {
        int d = dsub * 32 + l31;
#pragma unroll
        for (int ks = 0; ks < 4; ++ks) {
          int soff = ((ks * 2 + hi) ^ (d & 7)) << 3;
          bf16x8 vf = *(const bf16x8*)&Vs[cur][d * 64 + soff];
          o[dsub] = __builtin_amdgcn_mfma_f32_32x32x16_bf16(vf, pa[ks], o[dsub], 0, 0, 0);
        }
      }
      __builtin_amdgcn_s_setprio(0);
    }
  }

  // ---- epilogue: normalize, write Ab[b, qrow, h*128 + d]
  // o[dsub] reg r holds d = dsub*32 + (r&3) + 8*(r>>2) + 4*hi for THIS lane's
  // qrow -> 4 consecutive d per group of 4 regs = ushort4 stores.
  float inv = 1.f / l_prev;
  size_t base = ((size_t)(b * Sn + qrow)) * En + h * Dn;
#pragma unroll
  for (int dsub = 0; dsub < 4; ++dsub) {
#pragma unroll
    for (int g = 0; g < 4; ++g) {
      ushort4 pk;
      pk.x = f2bf(o[dsub][g * 4 + 0] * inv);
      pk.y = f2bf(o[dsub][g * 4 + 1] * inv);
      pk.z = f2bf(o[dsub][g * 4 + 2] * inv);
      pk.w = f2bf(o[dsub][g * 4 + 3] * inv);
      *(ushort4*)&Ab[base + dsub * 32 + g * 8 + hi * 4] = pk;
    }
  }
}

extern "C" void kernel_launch(void* const* d_in, const int* in_sizes, int n_in,
                              void* d_out, int out_size, void* d_ws, size_t ws_size,
                              hipStream_t stream) {
  const float* x  = (const float*)d_in[0];
  const float* Wq = (const float*)d_in[1];
  const float* Wk = (const float*)d_in[2];
  const float* Wv = (const float*)d_in[3];
  const float* Wo = (const float*)d_in[4];

  char* ws = (char*)d_ws;
  ushort* xb  = (ushort*)(ws + 0);           // 32 MiB  [Mtot, En]
  ushort* wqb = (ushort*)(ws + 33554432);    // 8 MiB
  ushort* wkb = (ushort*)(ws + 41943040);
  ushort* wvb = (ushort*)(ws + 50331648);
  ushort* wob = (ushort*)(ws + 58720256);
  ushort* Qb  = (ushort*)(ws + 67108864);    // 32 MiB
  ushort* Kb  = (ushort*)(ws + 100663296);   // 32 MiB
  ushort* Vt  = (ushort*)(ws + 134217728);   // 32 MiB  [B*En, Sn]
  ushort* Ab  = xb;                           // alias: xb dead after V GEMM

  // converts
  cvt_kernel<<<dim3(Mtot * En / 1024), 256, 0, stream>>>(x, xb);
  cvt_kernel<<<dim3(En * En / 1024), 256, 0, stream>>>(Wq, wqb);
  cvt_kernel<<<dim3(En * En / 1024), 256, 0, stream>>>(Wk, wkb);
  cvt_kernel<<<dim3(En * En / 1024), 256, 0, stream>>>(Wv, wvb);
  cvt_kernel<<<dim3(En * En / 1024), 256, 0, stream>>>(Wo, wob);

  dim3 ggrid(En / 128, Mtot / 128);
  // Q/K with fused RoPE (Q also gets softmax scale * log2e folded in)
  gemm_bt<3><<<ggrid, 256, 0, stream>>>(xb, wqb, (void*)Qb,
                                        0.08838834764831845f * 1.4426950408889634f);
  gemm_bt<3><<<ggrid, 256, 0, stream>>>(xb, wkb, (void*)Kb, 1.0f);
  gemm_bt<1><<<ggrid, 256, 0, stream>>>(xb, wvb, (void*)Vt, 0.f);

  flash_kernel<<<dim3(Bn * Hn * Sn / 128), 256, 0, stream>>>(Qb, Kb, Vt, Ab);

  gemm_bt<2><<<ggrid, 256, 0, stream>>>(Ab, wob, d_out, 0.f);
}

// Round 7
// 845.498 us; speedup vs baseline: 2.5828x; 2.5828x over previous
//
#include <hip/hip_runtime.h>

typedef float f32x4 __attribute__((ext_vector_type(4)));
typedef float f32x16 __attribute__((ext_vector_type(16)));
typedef short bf16x8 __attribute__((ext_vector_type(8)));

#define DEVI __device__ __forceinline__

// ---------- constants (problem shape is fixed) ----------
constexpr int Bn = 2;          // batch
constexpr int Sn = 4096;       // seq
constexpr int Hn = 16;         // heads
constexpr int Dn = 128;        // head dim
constexpr int En = 2048;       // d_model = Hn*Dn
constexpr int Mtot = Bn * Sn;  // 8192 token rows

DEVI unsigned short f2bf(float f) {
  unsigned u = __float_as_uint(f);
  u += 0x7fffu + ((u >> 16) & 1u);
  return (unsigned short)(u >> 16);
}
DEVI float bf2f(unsigned short h) {
  return __uint_as_float(((unsigned)h) << 16);
}
DEVI unsigned pk2(float a, float b) {
  return (unsigned)f2bf(a) | ((unsigned)f2bf(b) << 16);
}

DEVI void async16(const void* g, void* l) {
  __builtin_amdgcn_global_load_lds(
      (const __attribute__((address_space(1))) void*)g,
      (__attribute__((address_space(3))) void*)l, 16, 0, 0);
}

// Pack 8 fp32 P-values (S^T regs of one j-subtile) into the PV B-operand
// fragment for one mfma_32x32x16 k-slot (elem e -> j = hi*8 + e; lane keeps
// q-col = lane&31). shfl_xor(32) + select; proven correct in round 5.
DEVI bf16x8 pack_pa(float a0, float a1, float a2, float a3,
                    float a4, float a5, float a6, float a7, int hi) {
  unsigned w0 = pk2(a0, a1), w1 = pk2(a2, a3);
  unsigned y0 = pk2(a4, a5), y1 = pk2(a6, a7);
  unsigned x0 = __shfl_xor(w0, 32), x1 = __shfl_xor(w1, 32);
  unsigned z0 = __shfl_xor(y0, 32), z1 = __shfl_xor(y1, 32);
  union { unsigned u[4]; bf16x8 v; } r;
  r.u[0] = hi ? z0 : w0;
  r.u[1] = hi ? z1 : w1;
  r.u[2] = hi ? y0 : x0;
  r.u[3] = hi ? y1 : x1;
  return r.v;
}

// ---------- fp32 -> bf16 convert ----------
__global__ void cvt_kernel(const float* __restrict__ in, ushort* __restrict__ out) {
  size_t i = ((size_t)blockIdx.x * 256 + threadIdx.x) * 4;
  float4 v = *(const float4*)&in[i];
  ushort4 o;
  o.x = f2bf(v.x); o.y = f2bf(v.y); o.z = f2bf(v.z); o.w = f2bf(v.w);
  *(ushort4*)&out[i] = o;
}

// ---------- RoPE cos/sin table: tab[s*64 + pp] = (cos, sin) ----------
// Trig calls live HERE (few live regs -> no spill), not in the GEMM epilogue.
__global__ void rope_tab_kernel(float2* __restrict__ tab) {
  int i = blockIdx.x * 256 + threadIdx.x;  // 0..262143
  int s = i >> 6, pp = i & 63;
  float inv = exp2f(-(float)pp * (13.287712379549449f / 64.0f));
  float ang = (float)s * inv;
  tab[i] = make_float2(cosf(ang), sinf(ang));
}

// ---------- GEMM: C[M,N] = A[M,K] * B[N,K]^T, bf16 in, fp32 acc ----------
// EPI 1: bf16 transposed V: Vt[(b*En + n)*Sn + s]  (m = b*Sn + s)
// EPI 2: fp32 C row-major
// EPI 3: bf16 C row-major with fused RoPE (interleaved pairs) * scale,
//        cos/sin from precomputed table (NO transcendental calls here).
template <int EPI>
__global__ __launch_bounds__(256) void gemm_bt(const ushort* __restrict__ A,
                                               const ushort* __restrict__ Bm,
                                               void* __restrict__ Cv,
                                               const float2* __restrict__ tab,
                                               float scale) {
  __shared__ ushort As[128 * 64];
  __shared__ ushort Bs[128 * 64];
  const int t = threadIdx.x;
  const int lane = t & 63, w = t >> 6;
  const int ln = lane & 15, gq = lane >> 4;
  const int m0 = blockIdx.y * 128, n0 = blockIdx.x * 128;
  const int rm = (w >> 1) * 64, rn = (w & 1) * 64;
  f32x4 acc[4][4] = {};

  for (int k0 = 0; k0 < En; k0 += 64) {
#pragma unroll
    for (int rep = 0; rep < 4; ++rep) {
      int c = rep * 256 + t;       // chunk 0..1023 (16B each)
      int row = c >> 3, c8 = c & 7;
      async16(&A[(size_t)(m0 + row) * En + k0 + c8 * 8],
              (char*)As + (rep * 256 + w * 64) * 16);
      async16(&Bm[(size_t)(n0 + row) * En + k0 + c8 * 8],
              (char*)Bs + (rep * 256 + w * 64) * 16);
    }
    __syncthreads();
#pragma unroll
    for (int kk = 0; kk < 64; kk += 32) {
      bf16x8 af[4], bf[4];
#pragma unroll
      for (int i = 0; i < 4; ++i)
        af[i] = *(const bf16x8*)&As[(rm + i * 16 + ln) * 64 + kk + gq * 8];
#pragma unroll
      for (int j = 0; j < 4; ++j)
        bf[j] = *(const bf16x8*)&Bs[(rn + j * 16 + ln) * 64 + kk + gq * 8];
#pragma unroll
      for (int i = 0; i < 4; ++i)
#pragma unroll
        for (int j = 0; j < 4; ++j)
          acc[i][j] = __builtin_amdgcn_mfma_f32_16x16x32_bf16(af[i], bf[j], acc[i][j], 0, 0, 0);
    }
    __syncthreads();
  }

  if constexpr (EPI == 1) {
    ushort* Vt = (ushort*)Cv;
#pragma unroll
    for (int i = 0; i < 4; ++i) {
      int mrow = m0 + rm + i * 16 + gq * 4;   // token row (4 consecutive)
      int bb = mrow >> 12;                     // /Sn
      int ss = mrow & (Sn - 1);
#pragma unroll
      for (int j = 0; j < 4; ++j) {
        int col = n0 + rn + j * 16 + ln;       // e = h*128+d
        ushort4 pk;
        pk.x = f2bf(acc[i][j][0]); pk.y = f2bf(acc[i][j][1]);
        pk.z = f2bf(acc[i][j][2]); pk.w = f2bf(acc[i][j][3]);
        *(ushort4*)&Vt[((size_t)(bb * En + col)) * Sn + ss] = pk;
      }
    }
  } else if constexpr (EPI == 2) {
    float* C = (float*)Cv;
#pragma unroll
    for (int i = 0; i < 4; ++i) {
      int row0 = m0 + rm + i * 16 + gq * 4;
#pragma unroll
      for (int j = 0; j < 4; ++j) {
        int col = n0 + rn + j * 16 + ln;
#pragma unroll
        for (int r = 0; r < 4; ++r)
          C[(size_t)(row0 + r) * En + col] = acc[i][j][r];
      }
    }
  } else {
    // EPI 3: fused RoPE via table. Pair partner (col^1) lives on lane^1.
    ushort* C = (ushort*)Cv;
    const int odd = ln & 1;
#pragma unroll
    for (int i = 0; i < 4; ++i) {
      int row0 = m0 + rm + i * 16 + gq * 4;
#pragma unroll
      for (int j = 0; j < 4; ++j) {
        int col = n0 + rn + j * 16 + ln;
        int pp = (col & (Dn - 1)) >> 1;  // pair index within head, 0..63
#pragma unroll
        for (int r = 0; r < 4; ++r) {
          int row = row0 + r;
          float2 cs = tab[(size_t)(row & (Sn - 1)) * 64 + pp];
          float self = acc[i][j][r];
          float other = __shfl_xor(self, 1);
          float val = odd ? (self * cs.x + other * cs.y)
                          : (self * cs.x - other * cs.y);
          C[(size_t)row * En + col] = f2bf(val * scale);
        }
      }
    }
  }
}

// ---------- flash attention (causal), 32x32 swapped-QK^T, in-register P ----
// Q: [Mtot,En] bf16 (RoPE + 1/sqrt(d)*log2e fused in GEMM). K: [Mtot,En].
// Vt: [B*En, Sn] bf16 (V transposed). Out Ab: [Mtot, En] bf16.
// Block: 4 waves x 32 q-rows = 128 q-rows. KV tile = 64.
// K/V double-buffered (T3/T4): issue tile t+1's 8 gload_lds per wave, then
// wait vmcnt(8) (tile t retired, t+1 in flight) -- never vmcnt(0) mid-loop.
// LDS 64KB -> 2 blocks/CU (reg limit anyway; pinned via launch_bounds(256,2)).
// S^T = mfma32(K, Q): lane owns q-col = lane&31 end-to-end.
// PV as O^T = mfma32(A=V^T, B=P): C[m=d][n=q] keeps q on lanes.
// Ks swizzle: 16B-slot ^= (j&15); Vs: slot ^= (d&7) (both-sides rule #21).
__global__ __launch_bounds__(256, 2) void flash_kernel(const ushort* __restrict__ Qb,
                                                       const ushort* __restrict__ Kb,
                                                       const ushort* __restrict__ Vt,
                                                       ushort* __restrict__ Ab) {
  __shared__ ushort Ks[2][64 * 128];   // [buf][kv j][d], swizzled
  __shared__ ushort Vs[2][128 * 64];   // [buf][d][kv j], swizzled
  const int t = threadIdx.x;
  const int lane = t & 63, w = t >> 6;
  const int l31 = lane & 31, hi = lane >> 5;

  // XCD-chunked decode: orig%8 = xcd, 4 bh per xcd, heavy qtile first (LPT)
  const int orig = blockIdx.x;         // 0..1023
  const int pos = orig >> 3;           // 0..127
  const int bh = ((orig & 7) << 2) + (pos >> 5);
  const int qt = 31 - (pos & 31);      // heavy-first
  const int q0 = qt * 128;
  const int b = bh >> 4, h = bh & 15;

  const int qrow = q0 + w * 32 + l31;  // this lane's q column

  // Q B-fragments: qf[ks] covers d = ks*16 + hi*8 + {0..7}
  bf16x8 qf[8];
  {
    size_t qbase = ((size_t)(b * Sn + qrow)) * En + h * Dn + hi * 8;
#pragma unroll
    for (int ks = 0; ks < 8; ++ks)
      qf[ks] = *(const bf16x8*)&Qb[qbase + ks * 16];
  }

  f32x16 o[4] = {};                    // O^T: [dsub] C[m=d][n=q], q on lanes
  float m_prev = -1e30f, l_prev = 0.f;
  const int last = 2 * qt + 1;         // tiles tt=0..last, j0 = tt*64

  // stage tile jt0 (elements) into buffer bufi: 8 gload_lds per wave
  auto stage = [&](int jt0, int bufi) {
#pragma unroll
    for (int rep = 0; rep < 4; ++rep) {
      int c = rep * 256 + t;
      int krow = c >> 4, ksl = c & 15;
      int kc = ksl ^ (krow & 15);          // inverse swizzle on global chunk
      async16(&Kb[((size_t)(b * Sn + jt0 + krow)) * En + h * Dn + kc * 8],
              (char*)&Ks[bufi][0] + (rep * 256 + w * 64) * 16);
      int vrow = c >> 3, vsl = c & 7;
      int vc = vsl ^ (vrow & 7);
      async16(&Vt[((size_t)(b * En + h * Dn + vrow)) * Sn + jt0 + vc * 8],
              (char*)&Vs[bufi][0] + (rep * 256 + w * 64) * 16);
    }
  };

  stage(0, 0);  // prologue: tile 0 in flight

  for (int tt = 0; tt <= last; ++tt) {
    const int cur = tt & 1;
    const int j0 = tt << 6;
    // B1: all waves finished reading buf[cur^1] -> safe to overwrite
    __builtin_amdgcn_s_barrier();
    if (tt < last) {
      stage((tt + 1) << 6, cur ^ 1);                    // 8 new in flight
      asm volatile("s_waitcnt vmcnt(8)" ::: "memory");  // tile tt retired
    } else {
      asm volatile("s_waitcnt vmcnt(0)" ::: "memory");
    }
    // B2: every wave's tile-tt DMA retired -> LDS tile complete
    __builtin_amdgcn_s_barrier();
    __builtin_amdgcn_sched_barrier(0);

    // waves whose q range is entirely above this kv tile skip compute
    if (j0 <= q0 + w * 32 + 31) {
      // ---- S^T: C[m=j][n=q] via mfma32(K, Q), 2 j-subtiles, 8 k-slots
      f32x16 s0 = {}, s1 = {};
      __builtin_amdgcn_s_setprio(1);
#pragma unroll
      for (int ks = 0; ks < 8; ++ks) {
        int soff = ((ks * 2 + hi) ^ (l31 & 15)) << 3;
        bf16x8 kf0 = *(const bf16x8*)&Ks[cur][l31 * 128 + soff];
        bf16x8 kf1 = *(const bf16x8*)&Ks[cur][(32 + l31) * 128 + soff];
        s0 = __builtin_amdgcn_mfma_f32_32x32x16_bf16(kf0, qf[ks], s0, 0, 0, 0);
        s1 = __builtin_amdgcn_mfma_f32_32x32x16_bf16(kf1, qf[ks], s1, 0, 0, 0);
      }
      __builtin_amdgcn_s_setprio(0);

      // ---- online softmax (lane owns one q-col; partner lane^32 has the
      // complementary 32 of the 64 kv rows)
      float mx = -1e30f;
      if (j0 + 63 > q0 + w * 32) {   // masking needed for this wave
#pragma unroll
        for (int r = 0; r < 16; ++r) {
          int jj = j0 + (r & 3) + 8 * (r >> 2) + 4 * hi;
          if (jj > qrow) s0[r] = -1e30f;
          if (jj + 32 > qrow) s1[r] = -1e30f;
          mx = fmaxf(mx, fmaxf(s0[r], s1[r]));
        }
      } else {
#pragma unroll
        for (int r = 0; r < 16; ++r)
          mx = fmaxf(mx, fmaxf(s0[r], s1[r]));
      }
      mx = fmaxf(mx, __shfl_xor(mx, 32));

      float mn;
      if (__all(mx - m_prev <= 8.f)) {   // defer-max (T13)
        mn = m_prev;
      } else {
        mn = fmaxf(m_prev, mx);
        float alpha = exp2f(m_prev - mn);
        m_prev = mn;
        l_prev *= alpha;
#pragma unroll
        for (int d = 0; d < 4; ++d) o[d] *= alpha;
      }
      float sum = 0.f;
#pragma unroll
      for (int r = 0; r < 16; ++r) {
        float p0 = exp2f(s0[r] - mn);
        float p1 = exp2f(s1[r] - mn);
        s0[r] = p0; s1[r] = p1;
        sum += p0 + p1;
      }
      sum += __shfl_xor(sum, 32);
      l_prev += sum;

      // ---- P -> PV B-fragments in registers (no LDS round-trip)
      bf16x8 pa[4];
      pa[0] = pack_pa(s0[0], s0[1], s0[2], s0[3], s0[4], s0[5], s0[6], s0[7], hi);
      pa[1] = pack_pa(s0[8], s0[9], s0[10], s0[11], s0[12], s0[13], s0[14], s0[15], hi);
      pa[2] = pack_pa(s1[0], s1[1], s1[2], s1[3], s1[4], s1[5], s1[6], s1[7], hi);
      pa[3] = pack_pa(s1[8], s1[9], s1[10], s1[11], s1[12], s1[13], s1[14], s1[15], hi);

      // ---- PV as O^T: C[m=d][n=q] = sum_j V^T[d][j] P[j][q]
      __builtin_amdgcn_s_setprio(1);
#pragma unroll
      for (int dsub = 0; dsub < 4; ++dsub) {
        int d = dsub * 32 + l31;
#pragma unroll
        for (int ks = 0; ks < 4; ++ks) {
          int soff = ((ks * 2 + hi) ^ (d & 7)) << 3;
          bf16x8 vf = *(const bf16x8*)&Vs[cur][d * 64 + soff];
          o[dsub] = __builtin_amdgcn_mfma_f32_32x32x16_bf16(vf, pa[ks], o[dsub], 0, 0, 0);
        }
      }
      __builtin_amdgcn_s_setprio(0);
    }
  }

  // ---- epilogue: normalize, write Ab[b, qrow, h*128 + d]
  // o[dsub] reg r holds d = dsub*32 + (r&3) + 8*(r>>2) + 4*hi for THIS lane's
  // qrow -> 4 consecutive d per group of 4 regs = ushort4 stores.
  float inv = 1.f / l_prev;
  size_t base = ((size_t)(b * Sn + qrow)) * En + h * Dn;
#pragma unroll
  for (int dsub = 0; dsub < 4; ++dsub) {
#pragma unroll
    for (int g = 0; g < 4; ++g) {
      ushort4 pk;
      pk.x = f2bf(o[dsub][g * 4 + 0] * inv);
      pk.y = f2bf(o[dsub][g * 4 + 1] * inv);
      pk.z = f2bf(o[dsub][g * 4 + 2] * inv);
      pk.w = f2bf(o[dsub][g * 4 + 3] * inv);
      *(ushort4*)&Ab[base + dsub * 32 + g * 8 + hi * 4] = pk;
    }
  }
}

extern "C" void kernel_launch(void* const* d_in, const int* in_sizes, int n_in,
                              void* d_out, int out_size, void* d_ws, size_t ws_size,
                              hipStream_t stream) {
  const float* x  = (const float*)d_in[0];
  const float* Wq = (const float*)d_in[1];
  const float* Wk = (const float*)d_in[2];
  const float* Wv = (const float*)d_in[3];
  const float* Wo = (const float*)d_in[4];

  char* ws = (char*)d_ws;
  ushort* xb  = (ushort*)(ws + 0);           // 32 MiB  [Mtot, En]
  ushort* wqb = (ushort*)(ws + 33554432);    // 8 MiB
  ushort* wkb = (ushort*)(ws + 41943040);
  ushort* wvb = (ushort*)(ws + 50331648);
  ushort* wob = (ushort*)(ws + 58720256);
  ushort* Qb  = (ushort*)(ws + 67108864);    // 32 MiB
  ushort* Kb  = (ushort*)(ws + 100663296);   // 32 MiB
  ushort* Vt  = (ushort*)(ws + 134217728);   // 32 MiB  [B*En, Sn]
  ushort* Ab  = xb;                           // alias: xb dead after V GEMM
  // RoPE table (2 MiB) lives in d_out scratch: fully overwritten by the
  // final GEMM, and only read by the Q/K GEMMs before that.
  float2* tab = (float2*)d_out;

  // converts + rope table
  cvt_kernel<<<dim3(Mtot * En / 1024), 256, 0, stream>>>(x, xb);
  cvt_kernel<<<dim3(En * En / 1024), 256, 0, stream>>>(Wq, wqb);
  cvt_kernel<<<dim3(En * En / 1024), 256, 0, stream>>>(Wk, wkb);
  cvt_kernel<<<dim3(En * En / 1024), 256, 0, stream>>>(Wv, wvb);
  cvt_kernel<<<dim3(En * En / 1024), 256, 0, stream>>>(Wo, wob);
  rope_tab_kernel<<<dim3(Sn * 64 / 256), 256, 0, stream>>>(tab);

  dim3 ggrid(En / 128, Mtot / 128);
  // Q/K with fused RoPE (Q also gets softmax scale * log2e folded in)
  gemm_bt<3><<<ggrid, 256, 0, stream>>>(xb, wqb, (void*)Qb, tab,
                                        0.08838834764831845f * 1.4426950408889634f);
  gemm_bt<3><<<ggrid, 256, 0, stream>>>(xb, wkb, (void*)Kb, tab, 1.0f);
  gemm_bt<1><<<ggrid, 256, 0, stream>>>(xb, wvb, (void*)Vt, nullptr, 0.f);

  flash_kernel<<<dim3(Bn * Hn * Sn / 128), 256, 0, stream>>>(Qb, Kb, Vt, Ab);

  gemm_bt<2><<<ggrid, 256, 0, stream>>>(Ab, wob, d_out, nullptr, 0.f);
}